// Round 8
// baseline (132.173 us; speedup 1.0000x reference)
//
#include <hip/hip_runtime.h>

#define B 64
#define N 1024
#define E 16384
#define WPR 32          // words per adjacency row = N/32
#define NITER 5

// ---- workspace layout (bytes) ---- (NO memset: every region fully stored
// before any read; harness 0xAA poison harmless)
#define ADJ_OFF   0
#define ADJ_BYTES ((size_t)B * N * WPR * 4)
#define FEATS_OFF ADJ_BYTES
#define GRAM_OFF  (FEATS_OFF + (size_t)B * N * 4)

// Bit adjacency built in LDS, full rows STORED to global (stores-only => safe
// against workspace poison). R5-R7 measured ~9us.
__global__ void __launch_bounds__(1024) build_adj_k(const int* __restrict__ src,
                                                    const int* __restrict__ dst,
                                                    unsigned int* __restrict__ adj) {
    __shared__ unsigned int s_adj[512 * WPR];       // 64 KiB: 512 rows
    int t = threadIdx.x;
    int b = blockIdx.x >> 1;
    int half = blockIdx.x & 1;
    int row_base = half << 9;

    uint4* s4 = (uint4*)s_adj;
#pragma unroll
    for (int k = 0; k < 4; ++k) s4[t + k * 1024] = make_uint4(0, 0, 0, 0);
    __syncthreads();

    const int* sg = src + (size_t)b * E;
    const int* dg = dst + (size_t)b * E;
#pragma unroll
    for (int k = 0; k < 16; ++k) {
        int e = t + k * 1024;
        int s = sg[e];
        int d = dg[e];
        int r = s - row_base;
        if ((unsigned)r < 512u)
            atomicOr(&s_adj[r * WPR + (d >> 5)], 1u << (d & 31));  // idempotent dedup
    }
    __syncthreads();

    uint4* g4 = (uint4*)(adj + ((size_t)b * N + row_base) * WPR);
#pragma unroll
    for (int k = 0; k < 4; ++k) g4[t + k * 1024] = s4[t + k * 1024];
}

// Whole WL loop, one block per graph. R8: adjacency row lives in 32 VGPRs for
// the whole kernel (no u16 CSR: R7's 740K bank-conflict cycles came from its
// stride-32B gather); 12 barriers/iter; wave0 shfl combines replace serial
// t==0 sections; re-zeroing folded into slack regions.
__global__ void __launch_bounds__(1024) wl_mega_k(const unsigned int* __restrict__ adj,
                                                  const int* __restrict__ lab0,
                                                  const float* __restrict__ hw,
                                                  unsigned int* __restrict__ feats) {
    __shared__ int s_lab[N];
    __shared__ int s_hist[N];
    __shared__ int s_scan[N];
    __shared__ float s_grp[N];
    __shared__ int s_flag[N];
    __shared__ unsigned int s_feats[N];
    __shared__ int s_wsum[16];
    __shared__ float s_mn[17], s_mx[17];
    __shared__ int s_K;
    int b = blockIdx.x, t = threadIdx.x;
    int lane = t & 63, w = t >> 6;

    // ---- Phase A: row -> regs, deg, K, init labels + bincount ----
    uint4 r[8];
    const uint4* rowg = (const uint4*)(adj + ((size_t)b * N + t) * WPR);
#pragma unroll
    for (int k = 0; k < 8; ++k) r[k] = rowg[k];
    int dg = 0;
#pragma unroll
    for (int k = 0; k < 8; ++k)
        dg += __popc(r[k].x) + __popc(r[k].y) + __popc(r[k].z) + __popc(r[k].w);

    int km = dg;
#pragma unroll
    for (int o = 32; o > 0; o >>= 1) km = max(km, __shfl_down(km, o));
    if (lane == 0) s_wsum[w] = km;

    int l0 = lab0[(size_t)b * N + t];
    s_lab[t] = l0;
    s_feats[t] = 0;
    s_hist[t] = 0;
    s_flag[t] = 0;
    __syncthreads();                                        // A1
    if (w == 0) {
        int v = (lane < 16) ? s_wsum[lane] : 0;
#pragma unroll
        for (int m = 8; m >= 1; m >>= 1) v = max(v, __shfl_xor(v, m));
        if (lane == 0) s_K = v;
    }
    // init label bincount (labels < 16) via ballot: 16 atomics/wave
#pragma unroll
    for (int v = 0; v < 16; ++v) {
        unsigned long long m = __ballot(l0 == v);
        if (lane == v) {
            int c = __popcll(m);
            if (c) atomicAdd(&s_feats[v], (unsigned)c);
        }
    }
    __syncthreads();                                        // A2
    float Kf = (float)s_K;
    float w0 = hw[0], w1 = hw[1];

    // ---- Phase B: 5 WL iterations ----
    for (int it = 0; it < NITER; ++it) {
        // gather from reg-held bit row + exact-_rn hash (bitwise == numpy)
        int s = 0;
#pragma unroll
        for (int k = 0; k < 8; ++k) {
            unsigned int wv[4] = { r[k].x, r[k].y, r[k].z, r[k].w };
#pragma unroll
            for (int c2 = 0; c2 < 4; ++c2) {
                unsigned int word = wv[c2];
                int base = (k * 4 + c2) << 5;
                while (word) {
                    int j = __ffs(word) - 1;
                    word &= word - 1;
                    s += s_lab[base + j];
                }
            }
        }
        float t1 = __fmul_rn(__fmul_rn(Kf, w0), (float)s_lab[t]);
        float t2 = __fmul_rn(w1, __fsub_rn(__fadd_rn((float)s, (float)dg), Kf));
        float h  = __fadd_rn(t1, t2);

        // block min/max partials
        float mn = h, mx = h;
#pragma unroll
        for (int o = 32; o > 0; o >>= 1) {
            mn = fminf(mn, __shfl_down(mn, o));
            mx = fmaxf(mx, __shfl_down(mx, o));
        }
        if (lane == 0) { s_mn[w] = mn; s_mx[w] = mx; }
        __syncthreads();                                    // B1
        if (w == 0) {
            float a = (lane < 16) ? s_mn[lane] : 3.4e38f;
            float c = (lane < 16) ? s_mx[lane] : -3.4e38f;
#pragma unroll
            for (int m = 8; m >= 1; m >>= 1) {
                a = fminf(a, __shfl_xor(a, m));
                c = fmaxf(c, __shfl_xor(c, m));
            }
            if (lane == 0) { s_mn[16] = a; s_mx[16] = c; }
        }
        __syncthreads();                                    // B2
        float fmn = s_mn[16];
        float span = s_mx[16] - fmn;
        float scale = (span > 0.f) ? (1023.0f / span) : 0.f;
        int bucket = min((int)((h - fmn) * scale), 1023);   // order-preserving
        int off_in = atomicAdd(&s_hist[bucket], 1);
        __syncthreads();                                    // B3

        // inclusive scan of bucket sizes
        int f = s_hist[t];
#pragma unroll
        for (int d2 = 1; d2 < 64; d2 <<= 1) {
            int v = __shfl_up(f, d2);
            if (lane >= d2) f += v;
        }
        if (lane == 63) s_wsum[w] = f;
        __syncthreads();                                    // B4
        if (w == 0) {
            int orig = (lane < 16) ? s_wsum[lane] : 0;
            int v = orig;
#pragma unroll
            for (int d2 = 1; d2 < 16; d2 <<= 1) {
                int u = __shfl_up(v, d2);
                if (lane >= d2) v += u;
            }
            if (lane < 16) s_wsum[lane] = v - orig;         // exclusive
        }
        __syncthreads();                                    // B5
        s_scan[t] = f + s_wsum[w];
        __syncthreads();                                    // B6

        int start = s_scan[bucket] - s_hist[bucket];
        int end   = s_scan[bucket];
        s_grp[start + off_in] = h;
        __syncthreads();                                    // B7

        int c = start;              // lower buckets strictly less (monotone map)
        for (int k = start; k < end; ++k) c += (s_grp[k] < h);
        s_flag[c] = 1;              // class start (same class -> same c)
        s_hist[t] = 0;              // re-zero for next iter (no reader here)
        __syncthreads();                                    // B8

        // inclusive scan of class-start flags -> dense rank
        int f2 = s_flag[t];
#pragma unroll
        for (int d2 = 1; d2 < 64; d2 <<= 1) {
            int v = __shfl_up(f2, d2);
            if (lane >= d2) f2 += v;
        }
        if (lane == 63) s_wsum[w] = f2;
        __syncthreads();                                    // B9
        if (w == 0) {
            int orig = (lane < 16) ? s_wsum[lane] : 0;
            int v = orig;
#pragma unroll
            for (int d2 = 1; d2 < 16; d2 <<= 1) {
                int u = __shfl_up(v, d2);
                if (lane >= d2) v += u;
            }
            if (lane < 16) s_wsum[lane] = v - orig;
        }
        __syncthreads();                                    // B10
        s_scan[t] = f2 + s_wsum[w];
        s_flag[t] = 0;              // re-zero (own flag already consumed)
        __syncthreads();                                    // B11

        int rank = s_scan[c] - 1;
        s_lab[t] = rank;
        atomicAdd(&s_feats[rank], 1u);
        __syncthreads();                                    // B12
    }

    feats[(size_t)b * N + t] = s_feats[t];
}

// gram: one block per row i; f_i staged in LDS; wave w computes j=w*16..w*16+15.
// int math exact (dots < 2^24).
__global__ void __launch_bounds__(256) gram_k(const unsigned int* __restrict__ feats,
                                              float* __restrict__ gram) {
    __shared__ unsigned int s_fi[N];
    int i = blockIdx.x, t = threadIdx.x;
    int lane = t & 63, w = t >> 6;
    ((uint4*)s_fi)[t] = ((const uint4*)(feats + (size_t)i * N))[t];
    __syncthreads();
    for (int jj = 0; jj < 16; ++jj) {
        int j = w * 16 + jj;
        const uint4* fj = (const uint4*)(feats + (size_t)j * N);
        const uint4* fi = (const uint4*)s_fi;
        int s = 0;
#pragma unroll
        for (int k = 0; k < 4; ++k) {
            uint4 vb = fj[lane + k * 64];
            uint4 va = fi[lane + k * 64];
            s += (int)(va.x * vb.x) + (int)(va.y * vb.y)
               + (int)(va.z * vb.z) + (int)(va.w * vb.w);
        }
#pragma unroll
        for (int off = 32; off > 0; off >>= 1) s += __shfl_down(s, off);
        if (lane == 0) gram[i * B + j] = (float)s;
    }
}

__global__ void norm_k(const float* __restrict__ gram, float* __restrict__ out) {
    int idx = blockIdx.x * blockDim.x + threadIdx.x;
    if (idx >= B * B) return;
    int i = idx >> 6, j = idx & 63;
    out[idx] = gram[idx] / sqrtf(gram[i * B + i] * gram[j * B + j]);
}

extern "C" void kernel_launch(void* const* d_in, const int* in_sizes, int n_in,
                              void* d_out, int out_size, void* d_ws, size_t ws_size,
                              hipStream_t stream) {
    const int*   esrc = (const int*)d_in[0];
    const int*   edst = (const int*)d_in[1];
    const int*   lab0 = (const int*)d_in[2];
    const float* hw   = (const float*)d_in[3];

    char* ws = (char*)d_ws;
    unsigned int* adj   = (unsigned int*)(ws + ADJ_OFF);
    unsigned int* feats = (unsigned int*)(ws + FEATS_OFF);
    float*        gram  = (float*)(ws + GRAM_OFF);

    build_adj_k<<<B * 2, 1024, 0, stream>>>(esrc, edst, adj);
    wl_mega_k<<<B, 1024, 0, stream>>>(adj, lab0, hw, feats);
    gram_k<<<B, 256, 0, stream>>>(feats, gram);
    norm_k<<<(B * B + 255) / 256, 256, 0, stream>>>(gram, (float*)d_out);
}

// Round 9
// 128.154 us; speedup vs baseline: 1.0314x; 1.0314x over previous
//
#include <hip/hip_runtime.h>

#define B 64
#define N 1024
#define E 16384
#define WPR 32          // words per adjacency row = N/32
#define NITER 5
#define CSR_SLOTS (E + 2 * N)   // +2 u16 pad per node -> 36-byte lane stride

// ---- workspace layout (bytes) ---- (NO memset: every region fully stored
// before any read; harness 0xAA poison harmless)
#define ADJ_OFF   0
#define ADJ_BYTES ((size_t)B * N * WPR * 4)
#define FEATS_OFF ADJ_BYTES
#define GRAM_OFF  (FEATS_OFF + (size_t)B * N * 4)

// Bit adjacency built in LDS, full rows STORED to global (stores-only => safe
// against workspace poison). R5-R8 measured ~9us.
__global__ void __launch_bounds__(1024) build_adj_k(const int* __restrict__ src,
                                                    const int* __restrict__ dst,
                                                    unsigned int* __restrict__ adj) {
    __shared__ unsigned int s_adj[512 * WPR];       // 64 KiB: 512 rows
    int t = threadIdx.x;
    int b = blockIdx.x >> 1;
    int half = blockIdx.x & 1;
    int row_base = half << 9;

    uint4* s4 = (uint4*)s_adj;
#pragma unroll
    for (int k = 0; k < 4; ++k) s4[t + k * 1024] = make_uint4(0, 0, 0, 0);
    __syncthreads();

    const int* sg = src + (size_t)b * E;
    const int* dg = dst + (size_t)b * E;
#pragma unroll
    for (int k = 0; k < 16; ++k) {
        int e = t + k * 1024;
        int s = sg[e];
        int d = dg[e];
        int r = s - row_base;
        if ((unsigned)r < 512u)
            atomicOr(&s_adj[r * WPR + (d >> 5)], 1u << (d & 31));  // idempotent dedup
    }
    __syncthreads();

    uint4* g4 = (uint4*)(adj + ((size_t)b * N + row_base) * WPR);
#pragma unroll
    for (int k = 0; k < 4; ++k) g4[t + k * 1024] = s4[t + k * 1024];
}

// Whole WL loop, one block per graph, LDS-resident.
// R9: CSR gather restored (R8's per-iter bit-walk paid ~7x wave-divergence tax)
// with +2-u16-per-node padding: lane byte stride 36 -> bank stride 9 (odd) ->
// full 32-bank spread, killing R7's 16-way conflicts on the gather.
__global__ void __launch_bounds__(1024) wl_mega_k(const unsigned int* __restrict__ adj,
                                                  const int* __restrict__ lab0,
                                                  const float* __restrict__ hw,
                                                  unsigned int* __restrict__ feats) {
    __shared__ unsigned short s_nbr[CSR_SLOTS];     // 36 KB padded CSR
    __shared__ int s_lab[N];
    __shared__ int s_hist[N];
    __shared__ int s_scan[N];
    __shared__ float s_grp[N];
    __shared__ int s_flag[N];
    __shared__ unsigned int s_feats[N];
    __shared__ int s_wsum[16];
    __shared__ int s_kp[16];
    __shared__ float s_mn[17], s_mx[17];
    __shared__ int s_K;
    int b = blockIdx.x, t = threadIdx.x;
    int lane = t & 63, w = t >> 6;

    // ---- Phase A: row -> deg/CSR/K, init labels + bincount ----
    uint4 r[8];
    const uint4* rowg = (const uint4*)(adj + ((size_t)b * N + t) * WPR);
#pragma unroll
    for (int k = 0; k < 8; ++k) r[k] = rowg[k];
    int dg = 0;
#pragma unroll
    for (int k = 0; k < 8; ++k)
        dg += __popc(r[k].x) + __popc(r[k].y) + __popc(r[k].z) + __popc(r[k].w);

    // intra-wave inclusive scan of deg + wave max partials
    int f = dg;
#pragma unroll
    for (int d2 = 1; d2 < 64; d2 <<= 1) {
        int v = __shfl_up(f, d2);
        if (lane >= d2) f += v;
    }
    int km = dg;
#pragma unroll
    for (int o = 32; o > 0; o >>= 1) km = max(km, __shfl_down(km, o));
    if (lane == 63) s_wsum[w] = f;
    if (lane == 0)  s_kp[w] = km;

    int l0 = lab0[(size_t)b * N + t];
    s_lab[t] = l0;
    s_feats[t] = 0;
    s_hist[t] = 0;
    s_flag[t] = 0;
    __syncthreads();                                        // A1
    if (w == 0) {
        int orig = (lane < 16) ? s_wsum[lane] : 0;
        int v = orig;
#pragma unroll
        for (int d2 = 1; d2 < 16; d2 <<= 1) {
            int u = __shfl_up(v, d2);
            if (lane >= d2) v += u;
        }
        if (lane < 16) s_wsum[lane] = v - orig;             // exclusive wave base
        int kk = (lane < 16) ? s_kp[lane] : 0;
#pragma unroll
        for (int m = 8; m >= 1; m >>= 1) kk = max(kk, __shfl_xor(kk, m));
        if (lane == 0) s_K = kk;
    }
    // init label bincount (labels < 16) via ballot
#pragma unroll
    for (int v = 0; v < 16; ++v) {
        unsigned long long m = __ballot(l0 == v);
        if (lane == v) {
            int c = __popcll(m);
            if (c) atomicAdd(&s_feats[v], (unsigned)c);
        }
    }
    __syncthreads();                                        // A2
    int start = (f - dg) + s_wsum[w] + 2 * t;               // padded CSR start

    // pack own row's set bits ONCE -> u16 neighbor list
    {
        int idx = start;
#pragma unroll
        for (int k = 0; k < 8; ++k) {
            unsigned int wv[4] = { r[k].x, r[k].y, r[k].z, r[k].w };
#pragma unroll
            for (int c2 = 0; c2 < 4; ++c2) {
                unsigned int word = wv[c2];
                int base = (k * 4 + c2) << 5;
                while (word) {
                    int j = __ffs(word) - 1;
                    word &= word - 1;
                    s_nbr[idx++] = (unsigned short)(base + j);
                }
            }
        }
    }
    float Kf = (float)s_K;
    float w0 = hw[0], w1 = hw[1];
    __syncthreads();                                        // A3

    // ---- Phase B: 5 WL iterations ----
    for (int it = 0; it < NITER; ++it) {
        // seg gather (conflict-free lane spread) + exact-_rn hash (== numpy)
        int s = 0;
        for (int k = 0; k < dg; ++k) s += s_lab[s_nbr[start + k]];
        float t1 = __fmul_rn(__fmul_rn(Kf, w0), (float)s_lab[t]);
        float t2 = __fmul_rn(w1, __fsub_rn(__fadd_rn((float)s, (float)dg), Kf));
        float h  = __fadd_rn(t1, t2);

        // block min/max
        float mn = h, mx = h;
#pragma unroll
        for (int o = 32; o > 0; o >>= 1) {
            mn = fminf(mn, __shfl_down(mn, o));
            mx = fmaxf(mx, __shfl_down(mx, o));
        }
        if (lane == 0) { s_mn[w] = mn; s_mx[w] = mx; }
        __syncthreads();                                    // B1
        if (w == 0) {
            float a = (lane < 16) ? s_mn[lane] : 3.4e38f;
            float c = (lane < 16) ? s_mx[lane] : -3.4e38f;
#pragma unroll
            for (int m = 8; m >= 1; m >>= 1) {
                a = fminf(a, __shfl_xor(a, m));
                c = fmaxf(c, __shfl_xor(c, m));
            }
            if (lane == 0) { s_mn[16] = a; s_mx[16] = c; }
        }
        __syncthreads();                                    // B2
        float fmn = s_mn[16];
        float span = s_mx[16] - fmn;
        float scale = (span > 0.f) ? (1023.0f / span) : 0.f;
        int bucket = min((int)((h - fmn) * scale), 1023);   // order-preserving
        int off_in = atomicAdd(&s_hist[bucket], 1);
        __syncthreads();                                    // B3

        // inclusive scan of bucket sizes
        f = s_hist[t];
#pragma unroll
        for (int d2 = 1; d2 < 64; d2 <<= 1) {
            int v = __shfl_up(f, d2);
            if (lane >= d2) f += v;
        }
        if (lane == 63) s_wsum[w] = f;
        __syncthreads();                                    // B4
        if (w == 0) {
            int orig = (lane < 16) ? s_wsum[lane] : 0;
            int v = orig;
#pragma unroll
            for (int d2 = 1; d2 < 16; d2 <<= 1) {
                int u = __shfl_up(v, d2);
                if (lane >= d2) v += u;
            }
            if (lane < 16) s_wsum[lane] = v - orig;         // exclusive
        }
        __syncthreads();                                    // B5
        s_scan[t] = f + s_wsum[w];
        __syncthreads();                                    // B6

        int bs = s_scan[bucket] - s_hist[bucket];
        int be = s_scan[bucket];
        s_grp[bs + off_in] = h;
        __syncthreads();                                    // B7

        int c = bs;                 // lower buckets strictly less (monotone map)
        for (int k = bs; k < be; ++k) c += (s_grp[k] < h);
        s_flag[c] = 1;              // class start (same class -> same c)
        s_hist[t] = 0;              // re-zero for next iter (no reader here)
        __syncthreads();                                    // B8

        // inclusive scan of class-start flags -> dense rank
        int f2 = s_flag[t];
#pragma unroll
        for (int d2 = 1; d2 < 64; d2 <<= 1) {
            int v = __shfl_up(f2, d2);
            if (lane >= d2) f2 += v;
        }
        if (lane == 63) s_wsum[w] = f2;
        __syncthreads();                                    // B9
        if (w == 0) {
            int orig = (lane < 16) ? s_wsum[lane] : 0;
            int v = orig;
#pragma unroll
            for (int d2 = 1; d2 < 16; d2 <<= 1) {
                int u = __shfl_up(v, d2);
                if (lane >= d2) v += u;
            }
            if (lane < 16) s_wsum[lane] = v - orig;
        }
        __syncthreads();                                    // B10
        s_scan[t] = f2 + s_wsum[w];
        s_flag[t] = 0;              // re-zero (own flag already consumed)
        __syncthreads();                                    // B11

        int rank = s_scan[c] - 1;
        s_lab[t] = rank;
        atomicAdd(&s_feats[rank], 1u);
        __syncthreads();                                    // B12
    }

    feats[(size_t)b * N + t] = s_feats[t];
}

// gram: one block per row i; f_i staged in LDS; wave w computes j=w*16..w*16+15.
// int math exact (dots < 2^24).
__global__ void __launch_bounds__(256) gram_k(const unsigned int* __restrict__ feats,
                                              float* __restrict__ gram) {
    __shared__ unsigned int s_fi[N];
    int i = blockIdx.x, t = threadIdx.x;
    int lane = t & 63, w = t >> 6;
    ((uint4*)s_fi)[t] = ((const uint4*)(feats + (size_t)i * N))[t];
    __syncthreads();
    for (int jj = 0; jj < 16; ++jj) {
        int j = w * 16 + jj;
        const uint4* fj = (const uint4*)(feats + (size_t)j * N);
        const uint4* fi = (const uint4*)s_fi;
        int s = 0;
#pragma unroll
        for (int k = 0; k < 4; ++k) {
            uint4 vb = fj[lane + k * 64];
            uint4 va = fi[lane + k * 64];
            s += (int)(va.x * vb.x) + (int)(va.y * vb.y)
               + (int)(va.z * vb.z) + (int)(va.w * vb.w);
        }
#pragma unroll
        for (int off = 32; off > 0; off >>= 1) s += __shfl_down(s, off);
        if (lane == 0) gram[i * B + j] = (float)s;
    }
}

__global__ void norm_k(const float* __restrict__ gram, float* __restrict__ out) {
    int idx = blockIdx.x * blockDim.x + threadIdx.x;
    if (idx >= B * B) return;
    int i = idx >> 6, j = idx & 63;
    out[idx] = gram[idx] / sqrtf(gram[i * B + i] * gram[j * B + j]);
}

extern "C" void kernel_launch(void* const* d_in, const int* in_sizes, int n_in,
                              void* d_out, int out_size, void* d_ws, size_t ws_size,
                              hipStream_t stream) {
    const int*   esrc = (const int*)d_in[0];
    const int*   edst = (const int*)d_in[1];
    const int*   lab0 = (const int*)d_in[2];
    const float* hw   = (const float*)d_in[3];

    char* ws = (char*)d_ws;
    unsigned int* adj   = (unsigned int*)(ws + ADJ_OFF);
    unsigned int* feats = (unsigned int*)(ws + FEATS_OFF);
    float*        gram  = (float*)(ws + GRAM_OFF);

    build_adj_k<<<B * 2, 1024, 0, stream>>>(esrc, edst, adj);
    wl_mega_k<<<B, 1024, 0, stream>>>(adj, lab0, hw, feats);
    gram_k<<<B, 256, 0, stream>>>(feats, gram);
    norm_k<<<(B * B + 255) / 256, 256, 0, stream>>>(gram, (float*)d_out);
}